// Round 13
// baseline (73.819 us; speedup 1.0000x reference)
//
#include <hip/hip_runtime.h>
#include <math.h>

#define BB 16
#define NN 4096
#define DD 128
#define KK 1024
#define NPTS (BB*NN)

typedef _Float16 half8 __attribute__((ext_vector_type(8)));
typedef float f32x4 __attribute__((ext_vector_type(4)));

static __device__ __forceinline__ uint pack2(float a, float b) {
    _Float16 ha = (_Float16)a, hb = (_Float16)b;
    unsigned short ua = __builtin_bit_cast(unsigned short, ha);
    unsigned short ub = __builtin_bit_cast(unsigned short, hb);
    return (uint)ua | ((uint)ub << 16);
}

typedef __attribute__((address_space(1))) const void as1_void;
typedef __attribute__((address_space(3))) void as3_void;
static __device__ __forceinline__ void gld16(const void* g, void* l) {
    // async global->LDS, 16B/lane; LDS dest = uniform base + lane*16 (HW rule)
    __builtin_amdgcn_global_load_lds((as1_void*)g, (as3_void*)l, 16, 0, 0);
}

// counted waits + raw barrier (loads stay in flight ACROSS barriers — T3/T4)
#define VMWAIT4 asm volatile("s_waitcnt vmcnt(4)" ::: "memory")
#define VMWAIT2 asm volatile("s_waitcnt vmcnt(2)" ::: "memory")
#define VMWAIT0 asm volatile("s_waitcnt vmcnt(0)" ::: "memory")
#define LGKM0   asm volatile("s_waitcnt lgkmcnt(0)" ::: "memory")
#define RBARRIER do { __builtin_amdgcn_s_barrier(); asm volatile("" ::: "memory"); } while (0)
#define SCHEDB  __builtin_amdgcn_sched_barrier(0)

// ---------------- kernel 0a: centroid squared norms (wave per row, double shfl reduce) ----------------
__global__ void cnorm_kernel(const float* __restrict__ c, float* __restrict__ cnorm) {
    const int w = threadIdx.x >> 6, lane = threadIdx.x & 63;
    const int row = blockIdx.x * 4 + w;
    float2 v = ((const float2*)(c + (size_t)row * DD))[lane];
    double s = (double)v.x * v.x + (double)v.y * v.y;
#pragma unroll
    for (int m = 1; m < 64; m <<= 1) s += __shfl_xor(s, m);
    if (lane == 0) cnorm[row] = (float)s;
}

// ---------------- kernel 0b: pre-permute centroids into 16x16x32 B-fragment order ----------------
// Fragment (nt, c, lane) = cent row (nt*16 + (lane&15)), d in [c*32 + (lane>>4)*8, +8),
// split into fp16 hi + (lo*1024), packed as uint4 (layout HW-verified by R12's pass).
__global__ void cfrag_kernel(const float* __restrict__ cent,
                             uint4* __restrict__ cfh, uint4* __restrict__ cfl) {
    const int gid = blockIdx.x * 256 + threadIdx.x;   // [0, 64*4*64) = 16384
    const int nt = gid >> 8;
    const int c = (gid >> 6) & 3;
    const int lane = gid & 63;
    const int row = nt * 16 + (lane & 15);
    const int d0 = c * 32 + (lane >> 4) * 8;
    const float* src = cent + (size_t)row * DD + d0;
    float v[8];
#pragma unroll
    for (int i = 0; i < 8; ++i) v[i] = src[i];
    float lo[8];
#pragma unroll
    for (int i = 0; i < 8; ++i) {
        _Float16 h = (_Float16)v[i];
        lo[i] = (v[i] - (float)h) * 1024.f;
    }
    uint4 h4, l4;
    h4.x = pack2(v[0], v[1]); h4.y = pack2(v[2], v[3]);
    h4.z = pack2(v[4], v[5]); h4.w = pack2(v[6], v[7]);
    l4.x = pack2(lo[0], lo[1]); l4.y = pack2(lo[2], lo[3]);
    l4.z = pack2(lo[4], lo[5]); l4.w = pack2(lo[6], lo[7]);
    cfh[gid] = h4;
    cfl[gid] = l4;
}

// ---------------- kernel 1: nearest-centroid, 16x16x32 MFMA, M=32/wave, split-K x2 ----------------
// 1024 blocks x 4 waves; block = (pblk = bid>>1, kh = bid&1). Wave w owns 32 points
// [pblk*128 + w*32, +32) as two 16-row A-groups; block scans tiles [kh*32, +32).
// Per phase: 8 ds_read_b128 feed 24 MFMA (2x the reuse of R12 -> LDS pipe halved).
// R12's proven ring protocol: 4-slot ring, stage s -> slot s&3, phase t reads
// stage t and issues stage t+3, counted vmcnt(4) + raw barrier (tail 4->2->0).
// cr merged into one chain per group (R11-validated numerics).
__launch_bounds__(256, 4)
__global__ void assign_mfma9(const float* __restrict__ x,
                             const uint4* __restrict__ cfh, const uint4* __restrict__ cfl,
                             const float* __restrict__ cn,
                             float* __restrict__ bestv, int* __restrict__ bkv,
                             float* __restrict__ xn_arr) {
    __shared__ uint4 ring[4][8][64];   // [slot][frag-row: 0-3 hi(c), 4-7 lo(c)][lane]
    __shared__ float cnS[KK / 2];

    const int tid = threadIdx.x;
    const int lane = tid & 63;
    const int w = tid >> 6;
    const int l15 = lane & 15;
    const int lg = lane >> 4;          // k-group 0..3
    const int kh = blockIdx.x & 1;
    const int pblk = blockIdx.x >> 1;
    const int khBase = kh * 32;        // first tile of this k-half
    const int pbase = pblk * 128 + w * 32;

#define STAGE_ISSUE(S)                                                              \
    { const int s_ = (S); const int sl_ = s_ & 3;                                   \
      const size_t fb_ = ((size_t)(khBase + s_) * 4 + w) * 64 + lane;               \
      gld16(cfh + fb_, &ring[sl_][w][0]);                                           \
      gld16(cfl + fb_, &ring[sl_][w + 4][0]); }

    // prologue: issue stages 0..2 first (they fly under the cn/x loads)
#pragma unroll
    for (int s = 0; s < 3; ++s) STAGE_ISSUE(s)

    // this half's cn -> LDS (512 floats)
    ((float2*)cnS)[tid] = ((const float2*)(cn + kh * (KK / 2)))[tid];

    // A fragments: two 16-row groups; lane covers row base+g*16+l15, k = c*32+lg*8+i
    half8 ahiA[4], aloA[4], ahiB[4], aloB[4];
    float xsA = 0.f, xsB = 0.f;
    {
        const float4* xrA = (const float4*)(x + (size_t)(pbase + l15) * DD);
#pragma unroll
        for (int c = 0; c < 4; ++c) {
            float4 v0 = xrA[c * 8 + lg * 2];
            float4 v1 = xrA[c * 8 + lg * 2 + 1];
            float vv[8] = {v0.x, v0.y, v0.z, v0.w, v1.x, v1.y, v1.z, v1.w};
#pragma unroll
            for (int i = 0; i < 8; ++i) {
                _Float16 h = (_Float16)vv[i];
                ahiA[c][i] = h;
                aloA[c][i] = (_Float16)((vv[i] - (float)h) * 1024.f);
                xsA = fmaf(vv[i], vv[i], xsA);
            }
        }
        const float4* xrB = (const float4*)(x + (size_t)(pbase + 16 + l15) * DD);
#pragma unroll
        for (int c = 0; c < 4; ++c) {
            float4 v0 = xrB[c * 8 + lg * 2];
            float4 v1 = xrB[c * 8 + lg * 2 + 1];
            float vv[8] = {v0.x, v0.y, v0.z, v0.w, v1.x, v1.y, v1.z, v1.w};
#pragma unroll
            for (int i = 0; i < 8; ++i) {
                _Float16 h = (_Float16)vv[i];
                ahiB[c][i] = h;
                aloB[c][i] = (_Float16)((vv[i] - (float)h) * 1024.f);
                xsB = fmaf(vv[i], vv[i], xsB);
            }
        }
    }
    // lanes {l15, +16, +32, +48} hold disjoint k-quarters -> full row norms everywhere
    xsA += __shfl_xor(xsA, 16); xsA += __shfl_xor(xsA, 32);
    xsB += __shfl_xor(xsB, 16); xsB += __shfl_xor(xsB, 32);

    float best[8];
    int bk[8];
#pragma unroll
    for (int r = 0; r < 8; ++r) { best[r] = INFINITY; bk[r] = 0; }

    VMWAIT4;    // x/cn consumption already drained older gld16s; stage 0 landed
    LGKM0;      // own cnS ds_write done
    RBARRIER;   // all waves: stage 0 + cnS visible
    SCHEDB;

#define DO_PHASE(NT, SST, DOSTG, WAITSEQ)                                           \
    {                                                                               \
        const int sl_ = (NT) & 3;                                                   \
        f32x4 hhA, hhB, crA, crB;                                                   \
        _Pragma("unroll")                                                           \
        for (int i = 0; i < 4; ++i) { hhA[i] = 0.f; hhB[i] = 0.f; crA[i] = 0.f; crB[i] = 0.f; } \
        /* chunk 1: hi fragments */                                                 \
        uint4 b0 = ring[sl_][0][lane], b1 = ring[sl_][1][lane];                     \
        uint4 b2 = ring[sl_][2][lane], b3 = ring[sl_][3][lane];                     \
        if (DOSTG) STAGE_ISSUE(SST)                                                 \
        __builtin_amdgcn_s_setprio(1);                                              \
        hhA = __builtin_amdgcn_mfma_f32_16x16x32_f16(ahiA[0], __builtin_bit_cast(half8, b0), hhA, 0, 0, 0); \
        hhB = __builtin_amdgcn_mfma_f32_16x16x32_f16(ahiB[0], __builtin_bit_cast(half8, b0), hhB, 0, 0, 0); \
        crA = __builtin_amdgcn_mfma_f32_16x16x32_f16(aloA[0], __builtin_bit_cast(half8, b0), crA, 0, 0, 0); \
        crB = __builtin_amdgcn_mfma_f32_16x16x32_f16(aloB[0], __builtin_bit_cast(half8, b0), crB, 0, 0, 0); \
        hhA = __builtin_amdgcn_mfma_f32_16x16x32_f16(ahiA[1], __builtin_bit_cast(half8, b1), hhA, 0, 0, 0); \
        hhB = __builtin_amdgcn_mfma_f32_16x16x32_f16(ahiB[1], __builtin_bit_cast(half8, b1), hhB, 0, 0, 0); \
        crA = __builtin_amdgcn_mfma_f32_16x16x32_f16(aloA[1], __builtin_bit_cast(half8, b1), crA, 0, 0, 0); \
        crB = __builtin_amdgcn_mfma_f32_16x16x32_f16(aloB[1], __builtin_bit_cast(half8, b1), crB, 0, 0, 0); \
        hhA = __builtin_amdgcn_mfma_f32_16x16x32_f16(ahiA[2], __builtin_bit_cast(half8, b2), hhA, 0, 0, 0); \
        hhB = __builtin_amdgcn_mfma_f32_16x16x32_f16(ahiB[2], __builtin_bit_cast(half8, b2), hhB, 0, 0, 0); \
        crA = __builtin_amdgcn_mfma_f32_16x16x32_f16(aloA[2], __builtin_bit_cast(half8, b2), crA, 0, 0, 0); \
        crB = __builtin_amdgcn_mfma_f32_16x16x32_f16(aloB[2], __builtin_bit_cast(half8, b2), crB, 0, 0, 0); \
        hhA = __builtin_amdgcn_mfma_f32_16x16x32_f16(ahiA[3], __builtin_bit_cast(half8, b3), hhA, 0, 0, 0); \
        hhB = __builtin_amdgcn_mfma_f32_16x16x32_f16(ahiB[3], __builtin_bit_cast(half8, b3), hhB, 0, 0, 0); \
        crA = __builtin_amdgcn_mfma_f32_16x16x32_f16(aloA[3], __builtin_bit_cast(half8, b3), crA, 0, 0, 0); \
        crB = __builtin_amdgcn_mfma_f32_16x16x32_f16(aloB[3], __builtin_bit_cast(half8, b3), crB, 0, 0, 0); \
        __builtin_amdgcn_s_setprio(0);                                              \
        /* chunk 2: lo fragments (reuse b0..b3 registers) */                        \
        b0 = ring[sl_][4][lane]; b1 = ring[sl_][5][lane];                           \
        b2 = ring[sl_][6][lane]; b3 = ring[sl_][7][lane];                           \
        __builtin_amdgcn_s_setprio(1);                                              \
        crA = __builtin_amdgcn_mfma_f32_16x16x32_f16(ahiA[0], __builtin_bit_cast(half8, b0), crA, 0, 0, 0); \
        crB = __builtin_amdgcn_mfma_f32_16x16x32_f16(ahiB[0], __builtin_bit_cast(half8, b0), crB, 0, 0, 0); \
        crA = __builtin_amdgcn_mfma_f32_16x16x32_f16(ahiA[1], __builtin_bit_cast(half8, b1), crA, 0, 0, 0); \
        crB = __builtin_amdgcn_mfma_f32_16x16x32_f16(ahiB[1], __builtin_bit_cast(half8, b1), crB, 0, 0, 0); \
        crA = __builtin_amdgcn_mfma_f32_16x16x32_f16(ahiA[2], __builtin_bit_cast(half8, b2), crA, 0, 0, 0); \
        crB = __builtin_amdgcn_mfma_f32_16x16x32_f16(ahiB[2], __builtin_bit_cast(half8, b2), crB, 0, 0, 0); \
        crA = __builtin_amdgcn_mfma_f32_16x16x32_f16(ahiA[3], __builtin_bit_cast(half8, b3), crA, 0, 0, 0); \
        crB = __builtin_amdgcn_mfma_f32_16x16x32_f16(ahiB[3], __builtin_bit_cast(half8, b3), crB, 0, 0, 0); \
        __builtin_amdgcn_s_setprio(0);                                              \
        {   const float cnv_ = cnS[(NT) * 16 + l15];                                \
            const int kcur_ = (khBase + (NT)) * 16 + l15;                           \
            _Pragma("unroll")                                                       \
            for (int r = 0; r < 4; ++r) {                                           \
                float vA_ = cnv_ - 2.f * hhA[r] - 0.001953125f * crA[r];            \
                if (vA_ < best[r]) { best[r] = vA_; bk[r] = kcur_; }                \
                float vB_ = cnv_ - 2.f * hhB[r] - 0.001953125f * crB[r];            \
                if (vB_ < best[4 + r]) { best[4 + r] = vB_; bk[4 + r] = kcur_; }    \
            }                                                                       \
        }                                                                           \
        WAITSEQ;                                                                    \
    }

#define W4 do { VMWAIT4; RBARRIER; SCHEDB; } while (0)
#define W2 do { VMWAIT2; RBARRIER; SCHEDB; } while (0)
#define W0 do { VMWAIT0; RBARRIER; SCHEDB; } while (0)
#define WN do { } while (0)

#pragma unroll 1
    for (int t = 0; t < 29; ++t) {
        DO_PHASE(t, t + 3, 1, W4)
    }
    DO_PHASE(29, 0, 0, W2)   // outstanding {30,31} -> wait to 2: stage 30 landed
    DO_PHASE(30, 0, 0, W0)   // drain: stage 31 landed
    DO_PHASE(31, 0, 0, WN)   // last tile, no barrier
#undef DO_PHASE
#undef STAGE_ISSUE
#undef W4
#undef W2
#undef W0
#undef WN

    // argmin across the 16 centroid-columns within each 16-lane group
    // (masks < 16 keep lg fixed); numpy tie-break: smaller k
#pragma unroll
    for (int r = 0; r < 8; ++r) {
        float bv = best[r]; int bi = bk[r];
#pragma unroll
        for (int m = 1; m < 16; m <<= 1) {
            float ov = __shfl_xor(bv, m);
            int oi = __shfl_xor(bi, m);
            if (ov < bv || (ov == bv && oi < bi)) { bv = ov; bi = oi; }
        }
        best[r] = bv; bk[r] = bi;
    }

    // D layout (m89-verified): col = lane&15, row = (lane>>4)*4 + r  (per group)
    float xnv[8];
#pragma unroll
    for (int r = 0; r < 4; ++r) {
        xnv[r]     = __shfl(xsA, lg * 4 + r);   // row norms live on lanes l15 = row
        xnv[4 + r] = __shfl(xsB, lg * 4 + r);
    }

    if (l15 == 0) {
#pragma unroll
        for (int g = 0; g < 2; ++g)
#pragma unroll
            for (int r = 0; r < 4; ++r) {
                int p = pbase + g * 16 + lg * 4 + r;
                bestv[(size_t)kh * NPTS + p] = best[g * 4 + r];   // pre-xn partial min
                bkv[(size_t)kh * NPTS + p] = bk[g * 4 + r];
                if (kh == 0) xn_arr[p] = xnv[g * 4 + r];
            }
    }
}

// ---------------- kernel 2: merge halves + per-batch stats + histogram + normalize ----------------
__global__ void finalize_kernel(const float* __restrict__ bestv, const int* __restrict__ bkv,
                                const float* __restrict__ xn_arr,
                                const float* __restrict__ weights, float* __restrict__ out) {
    __shared__ float dS[NN];      // merged min distances
    __shared__ int   bkS[NN];     // merged argmin
    __shared__ float red[1024];
    __shared__ int hist[KK];
    __shared__ float bc[2];       // mean, thr
    const int b = blockIdx.x;
    const int tid = threadIdx.x;

    // merge the two k-halves (strict <: half-0 ks all smaller -> numpy first-min),
    // then sq = xn + best, d = sqrt(max(sq,0))  — R9-validated arithmetic order.
    float s = 0.f;
#pragma unroll
    for (int j = 0; j < NN / 1024; ++j) {
        int i = tid + 1024 * j;
        size_t gi = (size_t)b * NN + i;
        float b0 = bestv[gi], b1 = bestv[NPTS + gi];
        int k0 = bkv[gi], k1 = bkv[NPTS + gi];
        float bm = b0; int km = k0;
        if (b1 < bm) { bm = b1; km = k1; }
        float d = sqrtf(fmaxf(xn_arr[gi] + bm, 0.f));
        dS[i] = d; bkS[i] = km;
        s += d;
    }

    // pass A: mean (two-pass std to match numpy numerics)
    red[tid] = s;
    __syncthreads();
    for (int off = 512; off > 0; off >>= 1) {
        if (tid < off) red[tid] += red[tid + off];
        __syncthreads();
    }
    if (tid == 0) bc[0] = red[0] / (float)NN;
    __syncthreads();
    const float mean = bc[0];

    // pass B: sum of squared deviations -> thr = mean + std(ddof=1)
    float ss = 0.f;
#pragma unroll
    for (int j = 0; j < NN / 1024; ++j) {
        float v = dS[tid + 1024 * j] - mean;
        ss += v * v;
    }
    red[tid] = ss;
    __syncthreads();
    for (int off = 512; off > 0; off >>= 1) {
        if (tid < off) red[tid] += red[tid + off];
        __syncthreads();
    }
    if (tid == 0) bc[1] = mean + sqrtf(red[0] / (float)(NN - 1));

    // histogram of masked assignments
    hist[tid] = 0;
    __syncthreads();
    const float thr = bc[1];
#pragma unroll
    for (int j = 0; j < NN / 1024; ++j) {
        int i = tid + 1024 * j;
        if (dS[i] < thr) atomicAdd(&hist[bkS[i]], 1);
    }
    __syncthreads();

    // asmk = counts*weights; L2-normalize the row (one k per thread)
    const float a = (float)hist[tid] * weights[tid];
    red[tid] = a * a;
    __syncthreads();
    for (int off = 512; off > 0; off >>= 1) {
        if (tid < off) red[tid] += red[tid + off];
        __syncthreads();
    }
    const float norm = sqrtf(red[0]);
    const float scale = 1.f / fmaxf(norm, 1e-12f);
    out[(size_t)b * KK + tid] = a * scale;
}

extern "C" void kernel_launch(void* const* d_in, const int* in_sizes, int n_in,
                              void* d_out, int out_size, void* d_ws, size_t ws_size,
                              hipStream_t stream) {
    const float* x = (const float*)d_in[0];
    const float* cent = (const float*)d_in[1];
    const float* weights = (const float*)d_in[2];
    float* out = (float*)d_out;

    char* ws = (char*)d_ws;
    float* bestv  = (float*)(ws + 0);          // [2][NPTS]  512 KB
    int*   bkv    = (int*)  (ws + 524288);     // [2][NPTS]  512 KB
    float* xn_arr = (float*)(ws + 1048576);    // [NPTS]     256 KB
    float* cn     = (float*)(ws + 1310720);    // [KK]         4 KB
    uint4* cfh    = (uint4*)(ws + 1314816);    // 256 KB
    uint4* cfl    = (uint4*)(ws + 1576960);    // 256 KB

    cnorm_kernel<<<KK / 4, 256, 0, stream>>>(cent, cn);
    cfrag_kernel<<<64, 256, 0, stream>>>(cent, cfh, cfl);
    assign_mfma9<<<NPTS / 64, 256, 0, stream>>>(x, cfh, cfl, cn, bestv, bkv, xn_arr);
    finalize_kernel<<<BB, 1024, 0, stream>>>(bestv, bkv, xn_arr, weights, out);
}

// Round 14
// 72.472 us; speedup vs baseline: 1.0186x; 1.0186x over previous
//
#include <hip/hip_runtime.h>
#include <math.h>

#define BB 16
#define NN 4096
#define DD 128
#define KK 1024
#define NPTS (BB*NN)

typedef _Float16 half8 __attribute__((ext_vector_type(8)));
typedef float f32x4 __attribute__((ext_vector_type(4)));

static __device__ __forceinline__ uint pack2(float a, float b) {
    _Float16 ha = (_Float16)a, hb = (_Float16)b;
    unsigned short ua = __builtin_bit_cast(unsigned short, ha);
    unsigned short ub = __builtin_bit_cast(unsigned short, hb);
    return (uint)ua | ((uint)ub << 16);
}

typedef __attribute__((address_space(1))) const void as1_void;
typedef __attribute__((address_space(3))) void as3_void;
static __device__ __forceinline__ void gld16(const void* g, void* l) {
    // async global->LDS, 16B/lane; LDS dest = uniform base + lane*16 (HW rule)
    __builtin_amdgcn_global_load_lds((as1_void*)g, (as3_void*)l, 16, 0, 0);
}

// counted waits + raw barrier (loads stay in flight ACROSS barriers — T3/T4)
#define VMWAIT4 asm volatile("s_waitcnt vmcnt(4)" ::: "memory")
#define VMWAIT2 asm volatile("s_waitcnt vmcnt(2)" ::: "memory")
#define VMWAIT0 asm volatile("s_waitcnt vmcnt(0)" ::: "memory")
#define LGKM0   asm volatile("s_waitcnt lgkmcnt(0)" ::: "memory")
#define RBARRIER do { __builtin_amdgcn_s_barrier(); asm volatile("" ::: "memory"); } while (0)
#define SCHEDB  __builtin_amdgcn_sched_barrier(0)

// ---------------- kernel 0 (fused): centroid fragments + squared norms ----------------
// Blocks [0,64): pre-permute centroids into 16x16x32 B-fragment order
//   fragment (nt, c, lane) = cent row (nt*16 + (lane&15)), d in [c*32+(lane>>4)*8, +8),
//   split fp16 hi + (lo*1024), packed uint4 (HW-verified layout, R12/R13 pass).
// Blocks [64,320): cn[row] = ||c_row||^2 in double (wave per row).
__global__ void prep_kernel(const float* __restrict__ cent,
                            uint4* __restrict__ cfh, uint4* __restrict__ cfl,
                            float* __restrict__ cnorm) {
    if (blockIdx.x < 64) {
        const int gid = blockIdx.x * 256 + threadIdx.x;   // [0, 64*4*64) = 16384
        const int nt = gid >> 8;
        const int c = (gid >> 6) & 3;
        const int lane = gid & 63;
        const int row = nt * 16 + (lane & 15);
        const int d0 = c * 32 + (lane >> 4) * 8;
        const float* src = cent + (size_t)row * DD + d0;
        float v[8];
#pragma unroll
        for (int i = 0; i < 8; ++i) v[i] = src[i];
        float lo[8];
#pragma unroll
        for (int i = 0; i < 8; ++i) {
            _Float16 h = (_Float16)v[i];
            lo[i] = (v[i] - (float)h) * 1024.f;
        }
        uint4 h4, l4;
        h4.x = pack2(v[0], v[1]); h4.y = pack2(v[2], v[3]);
        h4.z = pack2(v[4], v[5]); h4.w = pack2(v[6], v[7]);
        l4.x = pack2(lo[0], lo[1]); l4.y = pack2(lo[2], lo[3]);
        l4.z = pack2(lo[4], lo[5]); l4.w = pack2(lo[6], lo[7]);
        cfh[gid] = h4;
        cfl[gid] = l4;
    } else {
        const int w = threadIdx.x >> 6, lane = threadIdx.x & 63;
        const int row = (blockIdx.x - 64) * 4 + w;
        float2 v = ((const float2*)(cent + (size_t)row * DD))[lane];
        double s = (double)v.x * v.x + (double)v.y * v.y;
#pragma unroll
        for (int m = 1; m < 64; m <<= 1) s += __shfl_xor(s, m);
        if (lane == 0) cnorm[row] = (float)s;
    }
}

// ---------------- kernel 1: nearest-centroid, 16x16x32 MFMA, 4 waves/SIMD ----------------
// R12's proven structure: 1024 blocks x 4 waves; wave w owns points [block*64+w*16,+16).
// 64 phases, 8KB stage (16 cents), 4-slot ring, stage s -> slot s&3; phase t reads
// stage t, issues stage t+3, counted vmcnt(4)+raw barrier (tail 4->2->0).
// This round: merged cr chain (R13-validated order), zero4 C-in for chain heads
// (eliminates per-phase acc init), hi/lo split reads with b-register reuse.
__launch_bounds__(256, 4)
__global__ void assign_mfma10(const float* __restrict__ x,
                              const uint4* __restrict__ cfh, const uint4* __restrict__ cfl,
                              const float* __restrict__ cn,
                              float* __restrict__ min_d, int* __restrict__ nearest) {
    __shared__ uint4 ring[4][8][64];   // [slot][frag-row: 0-3 hi(c), 4-7 lo(c)][lane]
    __shared__ float cnS[KK];

    const int tid = threadIdx.x;
    const int lane = tid & 63;
    const int w = tid >> 6;
    const int l15 = lane & 15;
    const int lg = lane >> 4;          // k-group 0..3
    const int p0 = blockIdx.x * 64 + w * 16;

#define STAGE_ISSUE(S)                                                              \
    { const int s_ = (S); const int sl_ = s_ & 3;                                   \
      gld16(cfh + ((size_t)s_ * 4 + w) * 64 + lane, &ring[sl_][w][0]);              \
      gld16(cfl + ((size_t)s_ * 4 + w) * 64 + lane, &ring[sl_][w + 4][0]); }

    // prologue: issue stages 0..2 first (fly under the cn/x loads)
#pragma unroll
    for (int s = 0; s < 3; ++s) STAGE_ISSUE(s)

    // cn -> LDS (consumed in epilogues; keeps the loop free of global loads)
    ((float4*)cnS)[tid] = ((const float4*)cn)[tid];

    // A fragments: lane covers row l15, k = c*32 + lg*8 + i (same split as R3-R13)
    half8 ahi[4], alo[4];
    float xs = 0.f;
    const float4* xrow = (const float4*)(x + (size_t)(p0 + l15) * DD);
#pragma unroll
    for (int c = 0; c < 4; ++c) {
        float4 v0 = xrow[c * 8 + lg * 2];
        float4 v1 = xrow[c * 8 + lg * 2 + 1];
        float vv[8] = {v0.x, v0.y, v0.z, v0.w, v1.x, v1.y, v1.z, v1.w};
#pragma unroll
        for (int i = 0; i < 8; ++i) {
            _Float16 h = (_Float16)vv[i];
            ahi[c][i] = h;
            alo[c][i] = (_Float16)((vv[i] - (float)h) * 1024.f);
            xs = fmaf(vv[i], vv[i], xs);
        }
    }
    // lanes {l15, l15+16, l15+32, l15+48} hold disjoint k-quarters of row l15
    xs += __shfl_xor(xs, 16);
    xs += __shfl_xor(xs, 32);          // every lane: ||x_{l15}||^2

    float best[4];
    int bk[4];
#pragma unroll
    for (int r = 0; r < 4; ++r) { best[r] = INFINITY; bk[r] = 0; }

    f32x4 zero4;                       // persistent zero C-in for MFMA chain heads
#pragma unroll
    for (int i = 0; i < 4; ++i) zero4[i] = 0.f;

    VMWAIT4;    // x/cn consumption drained older gld16s; stage 0 landed
    LGKM0;      // own cnS ds_write done
    RBARRIER;   // all waves: stage 0 + cnS visible
    SCHEDB;

#define DO_PHASE(NT, SST, DOSTG, WAITSEQ)                                           \
    {                                                                               \
        const int sl_ = (NT) & 3;                                                   \
        /* chunk 1: hi fragments -> hh chain + alo*bh half of cr (R13 order) */     \
        uint4 b0 = ring[sl_][0][lane], b1 = ring[sl_][1][lane];                     \
        uint4 b2 = ring[sl_][2][lane], b3 = ring[sl_][3][lane];                     \
        if (DOSTG) STAGE_ISSUE(SST)                                                 \
        f32x4 hh, cr;                                                               \
        __builtin_amdgcn_s_setprio(1);                                              \
        hh = __builtin_amdgcn_mfma_f32_16x16x32_f16(ahi[0], __builtin_bit_cast(half8, b0), zero4, 0, 0, 0); \
        cr = __builtin_amdgcn_mfma_f32_16x16x32_f16(alo[0], __builtin_bit_cast(half8, b0), zero4, 0, 0, 0); \
        hh = __builtin_amdgcn_mfma_f32_16x16x32_f16(ahi[1], __builtin_bit_cast(half8, b1), hh, 0, 0, 0);    \
        cr = __builtin_amdgcn_mfma_f32_16x16x32_f16(alo[1], __builtin_bit_cast(half8, b1), cr, 0, 0, 0);    \
        hh = __builtin_amdgcn_mfma_f32_16x16x32_f16(ahi[2], __builtin_bit_cast(half8, b2), hh, 0, 0, 0);    \
        cr = __builtin_amdgcn_mfma_f32_16x16x32_f16(alo[2], __builtin_bit_cast(half8, b2), cr, 0, 0, 0);    \
        hh = __builtin_amdgcn_mfma_f32_16x16x32_f16(ahi[3], __builtin_bit_cast(half8, b3), hh, 0, 0, 0);    \
        cr = __builtin_amdgcn_mfma_f32_16x16x32_f16(alo[3], __builtin_bit_cast(half8, b3), cr, 0, 0, 0);    \
        __builtin_amdgcn_s_setprio(0);                                              \
        /* chunk 2: lo fragments (reuse b0..b3) -> ahi*bl half of cr */             \
        b0 = ring[sl_][4][lane]; b1 = ring[sl_][5][lane];                           \
        b2 = ring[sl_][6][lane]; b3 = ring[sl_][7][lane];                           \
        __builtin_amdgcn_s_setprio(1);                                              \
        cr = __builtin_amdgcn_mfma_f32_16x16x32_f16(ahi[0], __builtin_bit_cast(half8, b0), cr, 0, 0, 0);    \
        cr = __builtin_amdgcn_mfma_f32_16x16x32_f16(ahi[1], __builtin_bit_cast(half8, b1), cr, 0, 0, 0);    \
        cr = __builtin_amdgcn_mfma_f32_16x16x32_f16(ahi[2], __builtin_bit_cast(half8, b2), cr, 0, 0, 0);    \
        cr = __builtin_amdgcn_mfma_f32_16x16x32_f16(ahi[3], __builtin_bit_cast(half8, b3), cr, 0, 0, 0);    \
        __builtin_amdgcn_s_setprio(0);                                              \
        {   const float cnv_ = cnS[(NT) * 16 + l15];                                \
            const int kcur_ = (NT) * 16 + l15;                                      \
            _Pragma("unroll")                                                       \
            for (int r = 0; r < 4; ++r) {                                           \
                float v_ = cnv_ - 2.f * hh[r] - 0.001953125f * cr[r];               \
                if (v_ < best[r]) { best[r] = v_; bk[r] = kcur_; }                  \
            }                                                                       \
        }                                                                           \
        WAITSEQ;                                                                    \
    }

#define W4 do { VMWAIT4; RBARRIER; SCHEDB; } while (0)
#define W2 do { VMWAIT2; RBARRIER; SCHEDB; } while (0)
#define W0 do { VMWAIT0; RBARRIER; SCHEDB; } while (0)
#define WN do { } while (0)

#pragma unroll 1
    for (int t = 0; t < 61; ++t) {
        DO_PHASE(t, t + 3, 1, W4)
    }
    DO_PHASE(61, 0, 0, W2)   // outstanding {62,63} -> wait to 2: stage 62 landed
    DO_PHASE(62, 0, 0, W0)   // drain: stage 63 landed
    DO_PHASE(63, 0, 0, WN)   // last tile, no barrier
#undef DO_PHASE
#undef STAGE_ISSUE
#undef W4
#undef W2
#undef W0
#undef WN

    // argmin across the 16 centroid-columns within each 16-lane group
    // (masks < 16 keep lg fixed); numpy tie-break: smaller k
#pragma unroll
    for (int r = 0; r < 4; ++r) {
        float bv = best[r]; int bi = bk[r];
#pragma unroll
        for (int m = 1; m < 16; m <<= 1) {
            float ov = __shfl_xor(bv, m);
            int oi = __shfl_xor(bi, m);
            if (ov < bv || (ov == bv && oi < bi)) { bv = ov; bi = oi; }
        }
        best[r] = bv; bk[r] = bi;
    }

    // D layout (m89-verified): col = lane&15, row = (lane>>4)*4 + r
    float xnv[4];
#pragma unroll
    for (int r = 0; r < 4; ++r)
        xnv[r] = __shfl(xs, lg * 4 + r);   // xs of point (lg*4+r) lives in lane (lg*4+r)

    if (l15 == 0) {
#pragma unroll
        for (int r = 0; r < 4; ++r) {
            int m = lg * 4 + r;
            float sq = xnv[r] + best[r];
            min_d[p0 + m] = sqrtf(fmaxf(sq, 0.f));
            nearest[p0 + m] = bk[r];
        }
    }
}

// ---------------- kernel 2: per-batch stats + histogram + normalize (1024 threads) ----------------
__global__ void finalize_kernel(const float* __restrict__ min_d, const int* __restrict__ nearest,
                                const float* __restrict__ weights, float* __restrict__ out) {
    __shared__ float red[1024];
    __shared__ int hist[KK];
    __shared__ float bc[2];  // mean, thr
    const int b = blockIdx.x;
    const int tid = threadIdx.x;
    const float* md = min_d + (size_t)b * NN;
    const int* nr = nearest + (size_t)b * NN;

    // pass A: mean (two-pass std to match numpy numerics)
    float s = 0.f;
#pragma unroll
    for (int j = 0; j < NN / 1024; ++j) s += md[tid + 1024 * j];
    red[tid] = s;
    __syncthreads();
    for (int off = 512; off > 0; off >>= 1) {
        if (tid < off) red[tid] += red[tid + off];
        __syncthreads();
    }
    if (tid == 0) bc[0] = red[0] / (float)NN;
    __syncthreads();
    const float mean = bc[0];

    // pass B: sum of squared deviations -> thr = mean + std(ddof=1)
    float ss = 0.f;
#pragma unroll
    for (int j = 0; j < NN / 1024; ++j) {
        float v = md[tid + 1024 * j] - mean;
        ss += v * v;
    }
    red[tid] = ss;
    __syncthreads();
    for (int off = 512; off > 0; off >>= 1) {
        if (tid < off) red[tid] += red[tid + off];
        __syncthreads();
    }
    if (tid == 0) bc[1] = mean + sqrtf(red[0] / (float)(NN - 1));

    // histogram of masked assignments
    hist[tid] = 0;
    __syncthreads();
    const float thr = bc[1];
#pragma unroll
    for (int j = 0; j < NN / 1024; ++j) {
        int i = tid + 1024 * j;
        if (md[i] < thr) atomicAdd(&hist[nr[i]], 1);
    }
    __syncthreads();

    // asmk = counts*weights; L2-normalize the row (one k per thread)
    const float a = (float)hist[tid] * weights[tid];
    red[tid] = a * a;
    __syncthreads();
    for (int off = 512; off > 0; off >>= 1) {
        if (tid < off) red[tid] += red[tid + off];
        __syncthreads();
    }
    const float norm = sqrtf(red[0]);
    const float scale = 1.f / fmaxf(norm, 1e-12f);
    out[(size_t)b * KK + tid] = a * scale;
}

extern "C" void kernel_launch(void* const* d_in, const int* in_sizes, int n_in,
                              void* d_out, int out_size, void* d_ws, size_t ws_size,
                              hipStream_t stream) {
    const float* x = (const float*)d_in[0];
    const float* cent = (const float*)d_in[1];
    const float* weights = (const float*)d_in[2];
    float* out = (float*)d_out;

    char* ws = (char*)d_ws;
    float* min_d   = (float*)(ws + 0);
    int*   nearest = (int*)  (ws + 262144);
    float* cn      = (float*)(ws + 524288);
    uint4* cfh     = (uint4*)(ws + 528384);
    uint4* cfl     = (uint4*)(ws + 790528);

    prep_kernel<<<320, 256, 0, stream>>>(cent, cfh, cfl, cn);
    assign_mfma10<<<NPTS / 64, 256, 0, stream>>>(x, cfh, cfl, cn, min_d, nearest);
    finalize_kernel<<<BB, 1024, 0, stream>>>(min_d, nearest, weights, out);
}